// Round 4
// baseline (282.653 us; speedup 1.0000x reference)
//
#include <hip/hip_runtime.h>
#include <hip/hip_bf16.h>

typedef __attribute__((ext_vector_type(8))) short short8;
typedef __attribute__((ext_vector_type(4))) float f32x4;
typedef __attribute__((ext_vector_type(8))) float f32x8;

#define IN_F 512
#define OUT_F 512
#define BM 64
#define BN 256
#define BK 64
#define PHI_STEPS 64
#define NSTEPS 72
#define NT 2
#define IMG_CHUNKS 2048          // (256 n) x (8 slots) 16B chunks per (nt,step) image
#define A_SZ (BM * BK)
#define B_SZ (BN * BK)

__device__ __forceinline__ short f2bf(float f) {
  __hip_bfloat16 h = __float2bfloat16(f);
  return __builtin_bit_cast(short, h);
}

__device__ __forceinline__ void glds16(const void* g, void* l) {
  // 16B global->LDS; LDS base wave-uniform, HW adds lane*16; global src per-lane.
  __builtin_amdgcn_global_load_lds(
      (const __attribute__((address_space(1))) unsigned int*)g,
      (__attribute__((address_space(3))) unsigned int*)l, 16, 0, 0);
}

__device__ __forceinline__ float bsrc(const float* __restrict__ w,
                                      const float* __restrict__ sb,
                                      int k, int col) {
  return (k < IN_F * 8) ? w[(size_t)k * OUT_F + col]
                        : sb[(size_t)(k - IN_F * 8) * OUT_F + col];
}

// K-map: phi steps s<64: k_orig = (oct*64 + s)*8 + j  (feature = oct*64+s, basis j)
//        tail  s>=64:    k_orig = 4096 + oct*64 + (s-64)*8 + j  (cos features)
__device__ __forceinline__ int korig(int s, int oct, int j) {
  return (s < PHI_STEPS) ? (oct * 64 + s) * 8 + j
                         : IN_F * 8 + oct * 64 + (s - PHI_STEPS) * 8 + j;
}

// Pre-swizzled bf16 B images matching the main kernel's LDS tile byte layout.
__global__ void __launch_bounds__(256) prep_b(const float* __restrict__ w,
                                              const float* __restrict__ sb,
                                              short* __restrict__ img) {
  const int D = blockIdx.x * 256 + threadIdx.x;  // chunk id
  const int ci = D & (IMG_CHUNKS - 1);
  const int im = D >> 11;                        // nt*NSTEPS + s
  const int s = im % NSTEPS;
  const int nt = im / NSTEPS;
  const int n = ci >> 3, slot = ci & 7;
  const int oct = slot ^ (n & 7);
  const int col = nt * BN + n;
  short8 v;
#pragma unroll
  for (int j = 0; j < 8; ++j) v[j] = f2bf(bsrc(w, sb, korig(s, oct, j), col));
  *(short8*)&img[(size_t)D * 8] = v;
}

template <bool PREB>
__global__ void __launch_bounds__(1024, 4) kan_main(
    const float* __restrict__ x, const float* __restrict__ rw,
    const float* __restrict__ rc, const float* __restrict__ w,
    const float* __restrict__ bias, const float* __restrict__ sb,
    const short* __restrict__ bimg, float* __restrict__ out) {
  // A: [64 rows][64 k] bf16, slot ^= row&7.  B: [256 n][64 k] bf16, slot ^= n&7.
  __shared__ __align__(16) short A_lds[2][A_SZ];   // 2 x 8 KB
  __shared__ __align__(16) short B_lds[2][B_SZ];   // 2 x 32 KB

  const int t = threadIdx.x, lane = t & 63, wid = t >> 6;
  const int m0 = blockIdx.x * BM;
  const int nt = blockIdx.y, n0 = nt * BN;

  if (wid >= 8) {
    // ================= producers: wave pw stages feature-octet pw =================
    const int pw = wid - 8;      // 0..7
    const int row = lane;        // 0..63
    const float* xrow = x + (size_t)(m0 + row) * IN_F + pw * 64;
    const float c2 = -10.259164f;  // -(8/3)^2 * log2(e)

    // x float8 ping-pong: group g (0..15), addr = xrow + (g&7)*8 (tail reuses phi x)
    f32x8 xgA, xgB;
    // param ring by step parity
    float4 prA0, prA1, pcA0, pcA1, prB0, prB1, pcB0, pcB1;

    auto loadX = [&](int g) {
      const f32x8 v = *(const f32x8*)(xrow + (g & 7) * 8);
      if ((g & 1) == 0) xgA = v; else xgB = v;
    };
    auto loadP = [&](int sc) {  // sc < PHI_STEPS; feat = pw*64 + sc
      const int feat = pw * 64 + sc;
      const float4 r0 = *(const float4*)(rw + feat * 8);
      const float4 r1 = *(const float4*)(rw + feat * 8 + 4);
      const float4 q0 = *(const float4*)(rc + feat * 8);
      const float4 q1 = *(const float4*)(rc + feat * 8 + 4);
      if (sc & 1) { prB0 = r0; prB1 = r1; pcB0 = q0; pcB1 = q1; }
      else        { prA0 = r0; prA1 = r1; pcA0 = q0; pcA1 = q1; }
    };
    auto stageB = [&](int sc) {
      const int buf = sc & 1;
      if (PREB) {
        const short* src = bimg + ((size_t)(nt * NSTEPS + sc) * IMG_CHUNKS + pw * 64 + lane) * 8;
        short* dst = &B_lds[buf][pw * 64 * 8];     // wave-uniform base
#pragma unroll
        for (int c = 0; c < 4; ++c)
          glds16(src + (size_t)512 * 8 * c, dst + 512 * 8 * c);
      } else {
        const int base_ci = pw * 64 + lane;
#pragma unroll
        for (int c = 0; c < 4; ++c) {
          const int ci = base_ci + 512 * c;
          const int n = ci >> 3, slot = ci & 7, oct = slot ^ (n & 7);
          short8 v;
#pragma unroll
          for (int j = 0; j < 8; ++j) v[j] = f2bf(bsrc(w, sb, korig(sc, oct, j), n0 + n));
          *(short8*)&B_lds[buf][n * BK + slot * 8] = v;
        }
      }
    };
    auto buildA = [&](int sc, int s8c) {  // s8c = sc&7, compile-time
      const int buf = sc & 1;
      short8 av;
      const int g = (sc < PHI_STEPS) ? (sc >> 3) : 8 + (sc - PHI_STEPS);
      const f32x8 xv = ((g & 1) == 0) ? xgA : xgB;
      if (sc < PHI_STEPS) {
        const float xs = xv[s8c];
        float4 R0, R1, Q0, Q1;
        if (sc & 1) { R0 = prB0; R1 = prB1; Q0 = pcB0; Q1 = pcB1; }
        else        { R0 = prA0; R1 = prA1; Q0 = pcA0; Q1 = pcA1; }
        const float rwv[8] = {R0.x, R0.y, R0.z, R0.w, R1.x, R1.y, R1.z, R1.w};
        const float rcv[8] = {Q0.x, Q0.y, Q0.z, Q0.w, Q1.x, Q1.y, Q1.z, Q1.w};
#pragma unroll
        for (int b = 0; b < 8; ++b) {
          const float z = fmaf(xs, rwv[b], -rcv[b]);
          av[b] = f2bf(exp2f(c2 * z * z));
        }
      } else {
#pragma unroll
        for (int j = 0; j < 8; ++j) av[j] = f2bf(__cosf(xv[j]));
      }
      *(short8*)&A_lds[buf][row * BK + (pw ^ (row & 7)) * 8] = av;
    };

    // -------- prologue: build step 0 into buf0 --------
    loadX(0);
    loadP(0); loadP(1);
    stageB(0);
    buildA(0, 0);
    __syncthreads();  // #0

    for (int so = 0; so < 9; ++so) {
#pragma unroll
      for (int s8 = 0; s8 < 8; ++s8) {
        const int s = so * 8 + s8;
        const int sc = s + 1;                 // step being built
        if (sc < NSTEPS) {
          const int sc2 = sc + 1;
          if (sc2 < NSTEPS) {
            const int g1 = (sc < PHI_STEPS) ? (sc >> 3) : 8 + (sc - PHI_STEPS);
            const int g2 = (sc2 < PHI_STEPS) ? (sc2 >> 3) : 8 + (sc2 - PHI_STEPS);
            if (g2 != g1) loadX(g2);          // 2-step x prefetch
          }
          if (s + 2 < PHI_STEPS) loadP(s + 2);  // 2-step param prefetch
          stageB(sc);                         // glds into buf[(s+1)&1]
          buildA(sc, (s8 + 1) & 7);           // exp/cos + ds_write
        }
        __syncthreads();                      // step boundary
      }
    }
    // producers exit; consumers store after final barrier
  } else {
    // ================= consumers: wave wid owns cols [wid*32, wid*32+32) =================
    f32x4 acc[4][2];
#pragma unroll
    for (int i = 0; i < 4; ++i)
#pragma unroll
      for (int j = 0; j < 2; ++j) acc[i][j] = (f32x4){0.f, 0.f, 0.f, 0.f};
    const int l15 = lane & 15, kb = lane >> 4;

    __syncthreads();  // #0
    for (int s = 0; s < NSTEPS; ++s) {
      const int buf = s & 1;
      const short* Ab = &A_lds[buf][0];
      const short* Bb = &B_lds[buf][0];
#pragma unroll
      for (int kk = 0; kk < 2; ++kk) {
        short8 af[4], bv[2];
        const int si = kk * 4 + kb;
#pragma unroll
        for (int mi = 0; mi < 4; ++mi) {
          const int r = mi * 16 + l15;
          af[mi] = *(const short8*)&Ab[r * BK + (si ^ (r & 7)) * 8];
        }
#pragma unroll
        for (int ni = 0; ni < 2; ++ni) {
          const int n = wid * 32 + ni * 16 + l15;
          bv[ni] = *(const short8*)&Bb[n * BK + (si ^ (n & 7)) * 8];
        }
#pragma unroll
        for (int mi = 0; mi < 4; ++mi)
#pragma unroll
          for (int ni = 0; ni < 2; ++ni)
            acc[mi][ni] = __builtin_amdgcn_mfma_f32_16x16x32_bf16(
                af[mi], bv[ni], acc[mi][ni], 0, 0, 0);
      }
      __syncthreads();
    }

    // -------- epilogue: bias + store --------
#pragma unroll
    for (int ni = 0; ni < 2; ++ni) {
      const int col = n0 + wid * 32 + ni * 16 + l15;
      const float bb = bias[col];
#pragma unroll
      for (int mi = 0; mi < 4; ++mi) {
        const int rb = m0 + mi * 16 + kb * 4;
#pragma unroll
        for (int r4 = 0; r4 < 4; ++r4)
          out[(size_t)(rb + r4) * OUT_F + col] = acc[mi][ni][r4] + bb;
      }
    }
  }
}

extern "C" void kernel_launch(void* const* d_in, const int* in_sizes, int n_in,
                              void* d_out, int out_size, void* d_ws, size_t ws_size,
                              hipStream_t stream) {
  const float* x    = (const float*)d_in[0];
  const float* rw   = (const float*)d_in[1];
  const float* rc   = (const float*)d_in[2];
  const float* w    = (const float*)d_in[3];
  const float* bias = (const float*)d_in[4];
  const float* sb   = (const float*)d_in[5];
  float* out = (float*)d_out;

  const int nrows = in_sizes[0] / IN_F;        // 8192
  dim3 grid(nrows / BM, NT);                   // (128, 2) = 256 blocks, 1/CU

  const size_t need = (size_t)NT * NSTEPS * IMG_CHUNKS * 16;  // 4.72 MB
  if (ws_size >= need) {
    short* img = (short*)d_ws;
    const int chunks = NT * NSTEPS * IMG_CHUNKS;
    prep_b<<<chunks / 256, 256, 0, stream>>>(w, sb, img);
    kan_main<true><<<grid, 1024, 0, stream>>>(x, rw, rc, w, bias, sb, img, out);
  } else {
    kan_main<false><<<grid, 1024, 0, stream>>>(x, rw, rc, w, bias, sb, nullptr, out);
  }
}

// Round 6
// 98.960 us; speedup vs baseline: 2.8562x; 2.8562x over previous
//
#include <hip/hip_runtime.h>
#include <hip/hip_bf16.h>

typedef __attribute__((ext_vector_type(8))) short short8;
typedef __attribute__((ext_vector_type(4))) float f32x4;

#define IN_F 512
#define OUT_F 512
#define BM 128
#define BN 128
#define BK 64
#define THREADS 512
#define PHI_STEPS 64
#define NSTEPS 72
#define NT 4
#define KSPLIT 2
#define SPL (NSTEPS / KSPLIT)            // 36 steps per block
#define IMG_CHUNKS 1024                  // (128 n) x (8 slots) 16B chunks per (nt,step)
#define IMG_SHORTS (IMG_CHUNKS * 8)
#define PART_ELEMS (8192 * OUT_F)        // one f32 partial plane

__device__ __forceinline__ short f2bf(float f) {
  __hip_bfloat16 h = __float2bfloat16(f);
  return __builtin_bit_cast(short, h);
}

__device__ __forceinline__ void glds16(const void* g, void* l) {
  // 16B global->LDS; LDS base wave-uniform (HW adds lane*16); global src per-lane.
  __builtin_amdgcn_global_load_lds(
      (const __attribute__((address_space(1))) unsigned int*)g,
      (__attribute__((address_space(3))) unsigned int*)l, 16, 0, 0);
}

__device__ __forceinline__ float bsrc(const float* __restrict__ w,
                                      const float* __restrict__ sb,
                                      int k, int col) {
  // k-map (R1, proven): k < 4096 -> w[(feat*8+basis)][col]; else cos row of sb.
  return (k < IN_F * 8) ? w[(size_t)k * OUT_F + col]
                        : sb[(size_t)(k - IN_F * 8) * OUT_F + col];
}

// bf16 B-images in the exact LDS tile byte order: per (nt, s), chunk ci = n*8+slot,
// slot = oct ^ (n&7), element j -> B[k = s*64 + oct*8 + j][nt*128 + n].
__global__ void __launch_bounds__(256) prep_b(const float* __restrict__ w,
                                              const float* __restrict__ sb,
                                              short* __restrict__ img) {
  const int D = blockIdx.x * 256 + threadIdx.x;   // global chunk id
  const int ci = D & (IMG_CHUNKS - 1);
  const int im = D >> 10;                         // nt*NSTEPS + s
  const int s = im % NSTEPS;
  const int nt = im / NSTEPS;
  const int n = ci >> 3, slot = ci & 7;
  const int oct = slot ^ (n & 7);
  const int col = nt * BN + n;
  short8 v;
#pragma unroll
  for (int j = 0; j < 8; ++j) v[j] = f2bf(bsrc(w, sb, s * 64 + oct * 8 + j, col));
  *(short8*)&img[(size_t)D * 8] = v;
}

// out = part0 + part1 + bias  (float4 vectorized)
__global__ void __launch_bounds__(256) reduce2(const float* __restrict__ part,
                                               const float* __restrict__ bias,
                                               float* __restrict__ out) {
  const int n4 = PART_ELEMS / 4;
  const float4* p0 = (const float4*)part;
  const float4* p1 = (const float4*)(part + PART_ELEMS);
  const float4* b4 = (const float4*)bias;
  float4* o4 = (float4*)out;
  for (int i = blockIdx.x * 256 + threadIdx.x; i < n4; i += gridDim.x * 256) {
    const float4 a = p0[i], b = p1[i], bb = b4[i & (OUT_F / 4 - 1)];
    float4 r;
    r.x = a.x + b.x + bb.x; r.y = a.y + b.y + bb.y;
    r.z = a.z + b.z + bb.z; r.w = a.w + b.w + bb.w;
    o4[i] = r;
  }
}

template <int KS, bool PREB>
__global__ void __launch_bounds__(THREADS, 4) kan_split(
    const float* __restrict__ x, const float* __restrict__ rw,
    const float* __restrict__ rc, const float* __restrict__ w,
    const float* __restrict__ bias, const float* __restrict__ sb,
    const short* __restrict__ bimg, float* __restrict__ dst) {
  // A: [128 rows][64 k] bf16, slot ^= row&7.  B: [128 n][64 k] bf16, slot ^= n&7.
  __shared__ __align__(16) short A_lds[BM * BK];   // 16 KB
  __shared__ __align__(16) short B_lds[BN * BK];   // 16 KB

  const int t = threadIdx.x, lane = t & 63, wid = t >> 6;
  const int wm = wid >> 2;      // 0..1 : 64 rows
  const int wn = wid & 3;       // 0..3 : 32 cols
  const int l15 = lane & 15, kb = lane >> 4;

  const int m0 = blockIdx.x * BM;
  const int nt = blockIdx.y, n0 = nt * BN;
  const int ks = blockIdx.z;
  const int s0 = ks * SPL;

  f32x4 acc[4][2];
#pragma unroll
  for (int i = 0; i < 4; ++i)
#pragma unroll
    for (int j = 0; j < 2; ++j) acc[i][j] = (f32x4){0.f, 0.f, 0.f, 0.f};

  // A staging: (row a_m, feature-octet a_il) x 2 row-iters
  const int a_il = t & 7;
  const int a_m = t >> 3;       // 0..63, +64 on iter 1
  // B fallback staging
  const int b_n = t & 127;
  const int b_o = t >> 7;

  const float c2 = -10.259164f;  // -(8/3)^2 * log2(e)  (exp(-b z^2) = exp2(c2 z^2))

  for (int si = 0; si < SPL; ++si) {
    const int s = s0 + si;
    __syncthreads();   // previous MFMA reads done before overwrite

    // ---- stage B: 2 x glds16 per thread (or fallback strided loads) ----
    if (PREB) {
      const short* src = bimg + ((size_t)(nt * NSTEPS + s) * IMG_CHUNKS + t) * 8;
      glds16(src, &B_lds[wid * 512]);
      glds16(src + IMG_SHORTS / 2, &B_lds[IMG_SHORTS / 2 + wid * 512]);
    }

    // ---- stage A: phi / cos ----
    if (s < PHI_STEPS) {
      const int feat = s * 8 + a_il;
      const float4 rw0 = *(const float4*)(rw + feat * 8);
      const float4 rw1 = *(const float4*)(rw + feat * 8 + 4);
      const float4 rc0 = *(const float4*)(rc + feat * 8);
      const float4 rc1 = *(const float4*)(rc + feat * 8 + 4);
      const float rwv[8] = {rw0.x, rw0.y, rw0.z, rw0.w, rw1.x, rw1.y, rw1.z, rw1.w};
      const float rcv[8] = {rc0.x, rc0.y, rc0.z, rc0.w, rc1.x, rc1.y, rc1.z, rc1.w};
#pragma unroll
      for (int iter = 0; iter < 2; ++iter) {
        const int m = a_m + iter * 64;
        const float xv = x[(size_t)(m0 + m) * IN_F + feat];
        short8 av;
#pragma unroll
        for (int b = 0; b < 8; ++b) {
          const float z = fmaf(xv, rwv[b], -rcv[b]);
          av[b] = f2bf(exp2f(c2 * z * z));
        }
        *(short8*)&A_lds[m * BK + (a_il ^ (m & 7)) * 8] = av;
      }
    } else {
      const int f0 = (s - PHI_STEPS) * 64 + a_il * 8;
#pragma unroll
      for (int iter = 0; iter < 2; ++iter) {
        const int m = a_m + iter * 64;
        const float4 xa = *(const float4*)(x + (size_t)(m0 + m) * IN_F + f0);
        const float4 xb = *(const float4*)(x + (size_t)(m0 + m) * IN_F + f0 + 4);
        short8 av;
        av[0] = f2bf(__cosf(xa.x)); av[1] = f2bf(__cosf(xa.y));
        av[2] = f2bf(__cosf(xa.z)); av[3] = f2bf(__cosf(xa.w));
        av[4] = f2bf(__cosf(xb.x)); av[5] = f2bf(__cosf(xb.y));
        av[6] = f2bf(__cosf(xb.z)); av[7] = f2bf(__cosf(xb.w));
        *(short8*)&A_lds[m * BK + (a_il ^ (m & 7)) * 8] = av;
      }
    }

    if (!PREB) {
      const float* Bs = (s < PHI_STEPS) ? (w + (size_t)s * 64 * OUT_F)
                                        : (sb + (size_t)(s - PHI_STEPS) * 64 * OUT_F);
      const float* p0 = Bs + (b_o * 8) * OUT_F + n0 + b_n;
      const float* p1 = Bs + ((b_o + 4) * 8) * OUT_F + n0 + b_n;
      short8 v0, v1;
#pragma unroll
      for (int j = 0; j < 8; ++j) { v0[j] = f2bf(p0[j * OUT_F]); v1[j] = f2bf(p1[j * OUT_F]); }
      *(short8*)&B_lds[b_n * BK + (b_o ^ (b_n & 7)) * 8] = v0;
      *(short8*)&B_lds[b_n * BK + ((b_o + 4) ^ (b_n & 7)) * 8] = v1;
    }

    __syncthreads();   // drains glds (vmcnt0) + ds_writes

    // ---- 16 MFMA per wave ----
#pragma unroll
    for (int kk = 0; kk < 2; ++kk) {
      short8 af[4], bv[2];
      const int slotk = kk * 4 + kb;
#pragma unroll
      for (int mi = 0; mi < 4; ++mi) {
        const int r = wm * 64 + mi * 16 + l15;
        af[mi] = *(const short8*)&A_lds[r * BK + (slotk ^ (r & 7)) * 8];
      }
#pragma unroll
      for (int ni = 0; ni < 2; ++ni) {
        const int n = wn * 32 + ni * 16 + l15;
        bv[ni] = *(const short8*)&B_lds[n * BK + (slotk ^ (n & 7)) * 8];
      }
#pragma unroll
      for (int mi = 0; mi < 4; ++mi)
#pragma unroll
        for (int ni = 0; ni < 2; ++ni)
          acc[mi][ni] = __builtin_amdgcn_mfma_f32_16x16x32_bf16(
              af[mi], bv[ni], acc[mi][ni], 0, 0, 0);
    }
  }

  // ---- epilogue ----
#pragma unroll
  for (int ni = 0; ni < 2; ++ni) {
    const int col = n0 + wn * 32 + ni * 16 + l15;
    const float bb = (KS == 1) ? bias[col] : 0.f;
#pragma unroll
    for (int mi = 0; mi < 4; ++mi) {
      const int rb = m0 + wm * 64 + mi * 16 + kb * 4;
#pragma unroll
      for (int r4 = 0; r4 < 4; ++r4) {
        const size_t idx = (size_t)(rb + r4) * OUT_F + col;
        if (KS == 1) dst[idx] = acc[mi][ni][r4] + bb;
        else         dst[(size_t)ks * PART_ELEMS + idx] = acc[mi][ni][r4];
      }
    }
  }
}

extern "C" void kernel_launch(void* const* d_in, const int* in_sizes, int n_in,
                              void* d_out, int out_size, void* d_ws, size_t ws_size,
                              hipStream_t stream) {
  const float* x    = (const float*)d_in[0];
  const float* rw   = (const float*)d_in[1];
  const float* rc   = (const float*)d_in[2];
  const float* w    = (const float*)d_in[3];
  const float* bias = (const float*)d_in[4];
  const float* sb   = (const float*)d_in[5];
  float* out = (float*)d_out;

  const int nrows = in_sizes[0] / IN_F;  // 8192

  const size_t img_bytes  = (size_t)NT * NSTEPS * IMG_SHORTS * sizeof(short);  // 4.72 MB
  const size_t part_bytes = (size_t)KSPLIT * PART_ELEMS * sizeof(float);       // 33.5 MB
  const int img_chunks_total = NT * NSTEPS * IMG_CHUNKS;

  if (ws_size >= img_bytes + part_bytes) {
    short* img = (short*)d_ws;
    float* part = (float*)((char*)d_ws + img_bytes);
    prep_b<<<img_chunks_total / 256, 256, 0, stream>>>(w, sb, img);
    dim3 grid(nrows / BM, NT, KSPLIT);   // (64, 4, 2) = 512 blocks
    kan_split<KSPLIT, true><<<grid, THREADS, 0, stream>>>(x, rw, rc, w, bias, sb, img, part);
    reduce2<<<2048, 256, 0, stream>>>(part, bias, out);
  } else if (ws_size >= img_bytes) {
    short* img = (short*)d_ws;
    prep_b<<<img_chunks_total / 256, 256, 0, stream>>>(w, sb, img);
    dim3 grid(nrows / BM, NT, 1);
    kan_split<1, true><<<grid, THREADS, 0, stream>>>(x, rw, rc, w, bias, sb, img, out);
  } else {
    dim3 grid(nrows / BM, NT, 1);
    kan_split<1, false><<<grid, THREADS, 0, stream>>>(x, rw, rc, w, bias, sb, nullptr, out);
  }
}

// Round 7
// 85.146 us; speedup vs baseline: 3.3196x; 1.1622x over previous
//
#include <hip/hip_runtime.h>
#include <hip/hip_bf16.h>

typedef __attribute__((ext_vector_type(8))) short short8;
typedef __attribute__((ext_vector_type(4))) float f32x4;

#define IN_F 512
#define OUT_F 512
#define BM 64
#define BN 512
#define BK 64
#define THREADS 512
#define PHI_STEPS 64
#define NSTEPS 72
#define KSPLIT 2
#define SPL (NSTEPS / KSPLIT)            // 36 steps per block
#define IMG_CHUNKS 4096                  // (512 n) x (8 slots) 16B chunks per step
#define A_SH (BM * BK)                   // 4096 shorts = 8 KB
#define B_SH (BN * BK)                   // 32768 shorts = 64 KB
#define PART_ELEMS (8192 * OUT_F)        // one f32 partial plane

__device__ __forceinline__ short f2bf(float f) {
  __hip_bfloat16 h = __float2bfloat16(f);
  return __builtin_bit_cast(short, h);
}

__device__ __forceinline__ void glds16(const void* g, void* l) {
  // 16B global->LDS; LDS base wave-uniform (HW adds lane*16); global src per-lane.
  __builtin_amdgcn_global_load_lds(
      (const __attribute__((address_space(1))) unsigned int*)g,
      (__attribute__((address_space(3))) unsigned int*)l, 16, 0, 0);
}

__device__ __forceinline__ float bsrc(const float* __restrict__ w,
                                      const float* __restrict__ sb,
                                      int k, int col) {
  // k-map: k < 4096 -> w[k][col] (k = feat*8+basis); else cos row (k-4096) of sb.
  return (k < IN_F * 8) ? w[(size_t)k * OUT_F + col]
                        : sb[(size_t)(k - IN_F * 8) * OUT_F + col];
}

// bf16 B-images in exact LDS tile byte order: per step s, chunk ci = n*8+slot,
// slot = oct ^ (n&7); element j -> B[k = s*64 + oct*8 + j][n].  (tile addr = ci*16B)
__global__ void __launch_bounds__(256) prep_b(const float* __restrict__ w,
                                              const float* __restrict__ sb,
                                              short* __restrict__ img) {
  const int D = blockIdx.x * 256 + threadIdx.x;   // global chunk id
  const int ci = D & (IMG_CHUNKS - 1);
  const int s = D >> 12;
  const int n = ci >> 3, slot = ci & 7;
  const int oct = slot ^ (n & 7);
  short8 v;
#pragma unroll
  for (int j = 0; j < 8; ++j) v[j] = f2bf(bsrc(w, sb, s * 64 + oct * 8 + j, n));
  *(short8*)&img[(size_t)D * 8] = v;
}

// out += part  (float4)
__global__ void __launch_bounds__(256) reduce_add(const float* __restrict__ part,
                                                  float* __restrict__ out) {
  const int n4 = PART_ELEMS / 4;
  const float4* p4 = (const float4*)part;
  float4* o4 = (float4*)out;
  for (int i = blockIdx.x * 256 + threadIdx.x; i < n4; i += gridDim.x * 256) {
    float4 a = o4[i];
    const float4 b = p4[i];
    a.x += b.x; a.y += b.y; a.z += b.z; a.w += b.w;
    o4[i] = a;
  }
}

template <int KS, bool PREB>
__global__ void __launch_bounds__(THREADS, 2) kan_main(
    const float* __restrict__ x, const float* __restrict__ rw,
    const float* __restrict__ rc, const float* __restrict__ w,
    const float* __restrict__ bias, const float* __restrict__ sb,
    const short* __restrict__ bimg, float* __restrict__ out,
    float* __restrict__ part) {
  // A: [64 m][64 k] bf16, slot ^= m&7.  B: [512 n][64 k] bf16, slot ^= n&7.
  __shared__ __align__(16) short A_lds[2][A_SH];   // 16 KB
  __shared__ __align__(16) short B_lds[2][B_SH];   // 128 KB

  const int t = threadIdx.x, lane = t & 63, wid = t >> 6;
  const int l15 = lane & 15, kb = lane >> 4;
  const int m0 = blockIdx.x * BM;
  const int ks = (KS == 2) ? blockIdx.y : 0;
  const int s0 = ks * SPL;

  // A staging: thread -> (row a_m = t>>3, k-octet a_il = t&7), one short8 each.
  const int a_il = t & 7;
  const int a_m = t >> 3;
  const float c2 = -10.2591705f;  // -(8/3)^2 * log2(e)

  f32x4 acc[4][4];
#pragma unroll
  for (int i = 0; i < 4; ++i)
#pragma unroll
    for (int j = 0; j < 4; ++j) acc[i][j] = (f32x4){0.f, 0.f, 0.f, 0.f};

  // ---------------- staging helpers (pointer-based, no runtime-indexed arrays) ----
  auto stage = [&](int s, short* __restrict__ Ad, short* __restrict__ Bd) {
    // B: 8 x glds16 (pre-swizzled image) or fallback convert
    if (PREB) {
      const short* src = bimg + ((size_t)s * IMG_CHUNKS + t) * 8;
#pragma unroll
      for (int c = 0; c < 8; ++c)
        glds16(src + (size_t)c * 512 * 8, Bd + c * 4096 + wid * 512);
    } else {
#pragma unroll
      for (int c = 0; c < 8; ++c) {
        const int ci = c * 512 + t;
        const int n = ci >> 3, slot = ci & 7, oct = slot ^ (n & 7);
        short8 v;
#pragma unroll
        for (int j = 0; j < 8; ++j) v[j] = f2bf(bsrc(w, sb, s * 64 + oct * 8 + j, n));
        *(short8*)&Bd[ci * 8] = v;
      }
    }
    // A: phi or cos, one short8 per thread
    short8 av;
    if (s < PHI_STEPS) {
      const int feat = s * 8 + a_il;
      const float xv = x[(size_t)(m0 + a_m) * IN_F + feat];
      const float4 r0 = *(const float4*)(rw + feat * 8);
      const float4 r1 = *(const float4*)(rw + feat * 8 + 4);
      const float4 q0 = *(const float4*)(rc + feat * 8);
      const float4 q1 = *(const float4*)(rc + feat * 8 + 4);
      const float rwv[8] = {r0.x, r0.y, r0.z, r0.w, r1.x, r1.y, r1.z, r1.w};
      const float rcv[8] = {q0.x, q0.y, q0.z, q0.w, q1.x, q1.y, q1.z, q1.w};
#pragma unroll
      for (int b = 0; b < 8; ++b) {
        const float z = fmaf(xv, rwv[b], -rcv[b]);
        av[b] = f2bf(exp2f(c2 * z * z));
      }
    } else {
      const float* xp = x + (size_t)(m0 + a_m) * IN_F + (s - PHI_STEPS) * 64 + a_il * 8;
      const float4 xa = *(const float4*)xp;
      const float4 xb = *(const float4*)(xp + 4);
      av[0] = f2bf(__cosf(xa.x)); av[1] = f2bf(__cosf(xa.y));
      av[2] = f2bf(__cosf(xa.z)); av[3] = f2bf(__cosf(xa.w));
      av[4] = f2bf(__cosf(xb.x)); av[5] = f2bf(__cosf(xb.y));
      av[6] = f2bf(__cosf(xb.z)); av[7] = f2bf(__cosf(xb.w));
    }
    Ad[a_m * BK + (a_il ^ (a_m & 7)) * 8 + 0] = av[0];  // force addr reuse
    *(short8*)&Ad[a_m * BK + (a_il ^ (a_m & 7)) * 8] = av;
  };

  auto mfma_step = [&](const short* __restrict__ Ab, const short* __restrict__ Bb) {
#pragma unroll
    for (int kk = 0; kk < 2; ++kk) {
      const int sk = kk * 4 + kb;
      short8 af[4], bf[4];
#pragma unroll
      for (int mi = 0; mi < 4; ++mi) {
        const int r = mi * 16 + l15;
        af[mi] = *(const short8*)&Ab[r * BK + (sk ^ (r & 7)) * 8];
      }
#pragma unroll
      for (int ni = 0; ni < 4; ++ni) {
        const int n = wid * 64 + ni * 16 + l15;
        bf[ni] = *(const short8*)&Bb[n * BK + (sk ^ (n & 7)) * 8];
      }
#pragma unroll
      for (int mi = 0; mi < 4; ++mi)
#pragma unroll
        for (int ni = 0; ni < 4; ++ni)
          acc[mi][ni] = __builtin_amdgcn_mfma_f32_16x16x32_bf16(
              af[mi], bf[ni], acc[mi][ni], 0, 0, 0);
    }
  };

  // ---------------- pipelined loop: stage(s+1) || mfma(s), one barrier/step ----
  stage(s0, A_lds[0], B_lds[0]);
  __syncthreads();
#pragma unroll 2
  for (int si = 0; si < SPL; ++si) {
    const int cur = si & 1;
    if (si + 1 < SPL) stage(s0 + si + 1, A_lds[cur ^ 1], B_lds[cur ^ 1]);
    mfma_step(A_lds[cur], B_lds[cur]);
    __syncthreads();
  }

  // ---------------- epilogue ----------------
#pragma unroll
  for (int ni = 0; ni < 4; ++ni) {
    const int col = wid * 64 + ni * 16 + l15;
    const float bb = (KS == 1 || ks == 0) ? bias[col] : 0.f;
#pragma unroll
    for (int mi = 0; mi < 4; ++mi) {
      const int rb = m0 + mi * 16 + kb * 4;
#pragma unroll
      for (int r4 = 0; r4 < 4; ++r4) {
        const size_t idx = (size_t)(rb + r4) * OUT_F + col;
        if (KS == 1 || ks == 0) out[idx] = acc[mi][ni][r4] + bb;
        else                    part[idx] = acc[mi][ni][r4];
      }
    }
  }
}

extern "C" void kernel_launch(void* const* d_in, const int* in_sizes, int n_in,
                              void* d_out, int out_size, void* d_ws, size_t ws_size,
                              hipStream_t stream) {
  const float* x    = (const float*)d_in[0];
  const float* rw   = (const float*)d_in[1];
  const float* rc   = (const float*)d_in[2];
  const float* w    = (const float*)d_in[3];
  const float* bias = (const float*)d_in[4];
  const float* sb   = (const float*)d_in[5];
  float* out = (float*)d_out;

  const int nrows = in_sizes[0] / IN_F;  // 8192

  const size_t img_bytes  = (size_t)NSTEPS * IMG_CHUNKS * 16;        // 4.72 MB
  const size_t part_bytes = (size_t)PART_ELEMS * sizeof(float);      // 16.8 MB
  const int img_chunks_total = NSTEPS * IMG_CHUNKS;

  if (ws_size >= img_bytes + part_bytes) {
    short* img = (short*)d_ws;
    float* part = (float*)((char*)d_ws + img_bytes);
    prep_b<<<img_chunks_total / 256, 256, 0, stream>>>(w, sb, img);
    dim3 grid(nrows / BM, KSPLIT);       // (128, 2) = 256 blocks, 1/CU
    kan_main<KSPLIT, true><<<grid, THREADS, 0, stream>>>(x, rw, rc, w, bias, sb,
                                                         img, out, part);
    reduce_add<<<2048, 256, 0, stream>>>(part, out);
  } else if (ws_size >= part_bytes) {
    float* part = (float*)d_ws;
    dim3 grid(nrows / BM, KSPLIT);
    kan_main<KSPLIT, false><<<grid, THREADS, 0, stream>>>(x, rw, rc, w, bias, sb,
                                                          nullptr, out, part);
    reduce_add<<<2048, 256, 0, stream>>>(part, out);
  } else {
    dim3 grid(nrows / BM, 1);            // 128 blocks, serial-K fallback
    kan_main<1, false><<<grid, THREADS, 0, stream>>>(x, rw, rc, w, bias, sb,
                                                     nullptr, out, nullptr);
  }
}